// Round 13
// baseline (410.608 us; speedup 1.0000x reference)
//
#include <hip/hip_runtime.h>
#include <hip/hip_bf16.h>
#include <math.h>

// Problem constants
#define B_  4
#define T_  8192
#define H_  1024
#define NHEAD 16
#define DH  64
#define BT  (B_*T_)   // 32768 rows

typedef __attribute__((ext_vector_type(8))) short bf16x8;
typedef __attribute__((ext_vector_type(4))) float f32x4;
typedef __attribute__((ext_vector_type(2))) float f32x2;
typedef __attribute__((ext_vector_type(2))) unsigned short u16x2;
typedef __attribute__((ext_vector_type(4))) unsigned short u16x4;
typedef __attribute__((ext_vector_type(8))) unsigned short u16x8;

static __device__ __forceinline__ float bf2f(unsigned short u) {
  union { unsigned int i; float f; } x; x.i = ((unsigned int)u) << 16; return x.f;
}
static __device__ __forceinline__ unsigned short f2bf(float f) {
  union { float f; unsigned int i; } x; x.f = f;
  unsigned int r = x.i + 0x7fffu + ((x.i >> 16) & 1u);  // RNE
  return (unsigned short)(r >> 16);
}

#define GL2LDS(gptr, sptr) \
  __builtin_amdgcn_global_load_lds((const __attribute__((address_space(1))) void*)(gptr), \
                                   (__attribute__((address_space(3))) void*)(sptr), 16, 0, 0)

#define BAR() do { asm volatile("" ::: "memory"); __builtin_amdgcn_s_barrier(); \
                   asm volatile("" ::: "memory"); } while (0)

// ---------------------------------------------------------------- cvt fp32->bf16
__global__ void cvt_kernel(const float* __restrict__ in, unsigned short* __restrict__ out, int n4) {
  int i = blockIdx.x * blockDim.x + threadIdx.x;
  int stride = gridDim.x * blockDim.x;
  for (int idx = i; idx < n4; idx += stride) {
    float4 v = reinterpret_cast<const float4*>(in)[idx];
    u16x4 o;
    o.x = f2bf(v.x); o.y = f2bf(v.y); o.z = f2bf(v.z); o.w = f2bf(v.w);
    reinterpret_cast<u16x4*>(out)[idx] = o;
  }
}

// ---------------------------------------------------------------- 128x128 2-block/CU bf16 GEMM
// C[M,N] = A[M,K]*B[N,K]^T + bias ; M=32768, N=K=1024.
// r13 THEORY: r5/r6/r8/r12 all ~81us at 1 block/CU because per-tile LDS-read
// time (~2300cyc/CU) dwarfs MFMA (~620cyc/SIMD) and nothing overlaps it in a
// barrier-lockstep single block. Fix = CO-RESIDENCY (m114): 128^2 tile,
// BK=64, 4 waves (2x2 of 64x64), LDS 64KB dbuf, acc 64 regs -> ~150 VGPR
// -> 8 waves/CU = 2 blocks/CU; block A's LDS reads hide under block B's MFMA.
// Loop = simple 2-barrier form: {read 16 frags; 32 MFMA; BAR; stage t+2
// (8 gloads); vmcnt(8) drains t+1; BAR}. Tails: t=14 vmcnt(0), t=15 compute.
// SWIZZLE: r5-verbatim (128B rows, key row&7): linear gload dest (sr =
// (4*wid+lane>>3 per 32-row call), source col ((lane&7)*8)^((lane>>3)<<3));
// frag read col = ((lane>>4)*16 + ks*64) ^ ((lane&7)<<4). Verified 0-conflict.
// grid = (8,256) = 2048 blocks, XCD-bijective swizzle (2048%8==0).
__global__ __launch_bounds__(256, 2) void gemm128(
    const unsigned short* __restrict__ A,
    const unsigned short* __restrict__ Bm,
    const float* __restrict__ bias,
    unsigned short* __restrict__ C) {
  const int K = 1024, N = 1024;
  __shared__ char lds[65536];   // 2 buf x (A 16KB + B 16KB)
  const int tid = threadIdx.x, lane = tid & 63, wid = tid >> 6;
  const int orig = blockIdx.y * 8 + blockIdx.x;
  const int swz  = (orig & 7) * 256 + (orig >> 3);
  const int bm = (swz >> 3) * 128, bn = (swz & 7) * 128;
  const int wm = (wid >> 1) * 64, wn = (wid & 1) * 64;

  // staging: one GL2LDS call = 256 lanes x 16B = 4KB = 32 rows of 128B.
  // lane covers row sr (within 32-row group), swizzled source col.
  const int sr   = wid * 8 + (lane >> 3);                  // 0..31
  const int scol = ((lane & 7) * 8) ^ ((lane >> 3) << 3);  // bf16 elems
  const unsigned short* gA = A  + (size_t)(bm + sr) * K + scol;
  const unsigned short* gB = Bm + (size_t)(bn + sr) * K + scol;
  const int dstw = wid * 1024;

  // fragment read: col = ((lane>>4)*16 + ks*64) ^ ((lane&7)<<4)
  const int aswz = (lane & 7) << 4;
  const int arow0 = (wm + (lane & 15)) * 128;              // A row base (bytes)
  const int brow0 = 16384 + (wn + (lane & 15)) * 128;      // B row base (bytes)

  f32x4 acc[4][4];
#pragma unroll
  for (int nn = 0; nn < 4; ++nn) {
    float bv = bias[bn + wn + nn * 16 + (lane & 15)];
    f32x4 sp = {bv, bv, bv, bv};
#pragma unroll
    for (int mm = 0; mm < 4; ++mm) acc[mm][nn] = sp;
  }

  bf16x8 aF[4][2], bF[4][2];

  auto stA = [&](int buf, int kt) {          // 16KB = 4 gloads (32 rows each)
    char* d = lds + buf * 32768 + dstw;
    const unsigned short* g = gA + kt * 64;
#pragma unroll
    for (int gg = 0; gg < 4; ++gg)
      GL2LDS(g + (size_t)(gg * 32) * K, d + gg * 4096);
  };
  auto stB = [&](int buf, int kt) {
    char* d = lds + buf * 32768 + 16384 + dstw;
    const unsigned short* g = gB + kt * 64;
#pragma unroll
    for (int gg = 0; gg < 4; ++gg)
      GL2LDS(g + (size_t)(gg * 32) * K, d + gg * 4096);
  };
  auto loadFrags = [&](int buf) {            // 16 x ds_read_b128
#pragma unroll
    for (int f = 0; f < 4; ++f)
#pragma unroll
      for (int ks = 0; ks < 2; ++ks) {
        const int col = (((lane >> 4) * 16 + ks * 64) ^ aswz);
        aF[f][ks] = *(const bf16x8*)(lds + buf * 32768 + arow0 + f * 2048 + col);
        bF[f][ks] = *(const bf16x8*)(lds + buf * 32768 + brow0 + f * 2048 + col);
      }
  };
  auto mfma32 = [&]() {
    __builtin_amdgcn_s_setprio(1);
#pragma unroll
    for (int mm = 0; mm < 4; ++mm)
#pragma unroll
      for (int nn = 0; nn < 4; ++nn)
#pragma unroll
        for (int ks = 0; ks < 2; ++ks)
          acc[mm][nn] = __builtin_amdgcn_mfma_f32_16x16x32_bf16(
              aF[mm][ks], bF[nn][ks], acc[mm][nn], 0, 0, 0);
    __builtin_amdgcn_s_setprio(0);
  };

  // prologue: stage tiles 0 and 1 (8 gloads each, ordered)
  stA(0, 0); stB(0, 0);
  stA(1, 1); stB(1, 1);
  asm volatile("s_waitcnt vmcnt(8)" ::: "memory");   // tile 0 landed
  BAR();

#define KT(t, STG, DOW, WSTR)                                 \
  {                                                           \
    const int b_ = (t) & 1;                                   \
    loadFrags(b_);                                            \
    mfma32();                                                 \
    BAR();                                                    \
    if (STG) { stA(b_, (t) + 2); stB(b_, (t) + 2); }          \
    if (DOW) { asm volatile("s_waitcnt vmcnt(" WSTR ")" ::: "memory"); } \
    BAR();                                                    \
  }

  for (int t = 0; t < 14; ++t) KT(t, 1, 1, "8")
  KT(14, 0, 1, "0")
  {
    loadFrags(1);
    mfma32();
  }
#undef KT

  // epilogue: C write (r2-verified mapping)
  const int crow = bm + wm + (lane >> 4) * 4;
  const int ccol = bn + wn + (lane & 15);
#pragma unroll
  for (int mm = 0; mm < 4; ++mm)
#pragma unroll
    for (int j = 0; j < 4; ++j) {
      unsigned short* cp = C + (size_t)(crow + mm * 16 + j) * N + ccol;
#pragma unroll
      for (int nn = 0; nn < 4; ++nn) cp[nn * 16] = f2bf(acc[mm][nn][j]);
    }
}

// ---------------------------------------------------------------- phase1 (MFMA): U-partials + colsum
__global__ __launch_bounds__(256, 2) void phase1(
    const unsigned short* __restrict__ Pk,
    const unsigned short* __restrict__ Pv,
    const float* __restrict__ mask_attn,
    float* __restrict__ Upart,     // [8][64][64][64]
    float* __restrict__ cspart) {  // [8][64][64]
  const int chunk = blockIdx.x;
  const int nh = blockIdx.y;
  const int n = nh >> 4, h = nh & 15;
  const int tid = threadIdx.x, lane = tid & 63, wid = tid >> 6;
  __shared__ __align__(16) unsigned short ekT[64 * 256];  // 32 KB
  __shared__ __align__(16) unsigned short vpT[64 * 256];  // 32 KB

  f32x4 acc[5];
#pragma unroll
  for (int i = 0; i < 5; ++i) acc[i] = (f32x4){0.f, 0.f, 0.f, 0.f};
  bf16x8 ones;
#pragma unroll
  for (int j = 0; j < 8; ++j) ones[j] = (short)0x3f80;

  const int isV = tid >> 7;
  const int slot0 = tid & 127;
  const unsigned short* src = isV ? Pv : Pk;
  unsigned short* dstT = isV ? vpT : ekT;

  const int arow = wid * 16 + (lane & 15);
  const int aswz = ((arow & 7) ^ ((arow >> 3) & 7)) << 4;

  for (int stage = 0; stage < 4; ++stage) {
    if (stage) __syncthreads();
#pragma unroll
    for (int r = 0; r < 2; ++r) {
      const int slot = slot0 + r * 128;
      const int toct = slot >> 3;
      const int d0   = (slot & 7) * 8;
      const int tbase = chunk * 1024 + stage * 256 + toct * 8;
      u16x8 in[8];
#pragma unroll
      for (int s = 0; s < 8; ++s)
        in[s] = *(const u16x8*)(src + (size_t)(n * T_ + tbase + s) * H_ + h * DH + d0);
      if (!isV) {
#pragma unroll
        for (int s = 0; s < 8; ++s) {
          const float madd = -10000.f * (1.f - mask_attn[n * T_ + tbase + s]);
          u16x8 o;
#pragma unroll
          for (int j = 0; j < 8; ++j) o[j] = f2bf(__expf(bf2f(in[s][j]) + madd));
          in[s] = o;
        }
      }
#pragma unroll
      for (int i = 0; i < 8; ++i) {
        u16x8 o;
#pragma unroll
        for (int s = 0; s < 8; ++s) o[s] = in[s][i];
        const int d = d0 + i;
        const int boff = (toct * 16) ^ (((d & 7) ^ ((d >> 3) & 7)) << 4);
        *(u16x8*)((char*)dstT + d * 512 + boff) = o;
      }
    }
    __syncthreads();
#pragma unroll
    for (int kk = 0; kk < 8; ++kk) {
      const int koff = kk * 64 + (lane >> 4) * 16;
      bf16x8 af = *(const bf16x8*)((const char*)ekT + arow * 512 + (koff ^ aswz));
      acc[4] = __builtin_amdgcn_mfma_f32_16x16x32_bf16(af, ones, acc[4], 0, 0, 0);
#pragma unroll
      for (int nn = 0; nn < 4; ++nn) {
        const int brow = nn * 16 + (lane & 15);
        const int bswz = ((brow & 7) ^ ((brow >> 3) & 7)) << 4;
        bf16x8 bf_ = *(const bf16x8*)((const char*)vpT + brow * 512 + (koff ^ bswz));
        acc[nn] = __builtin_amdgcn_mfma_f32_16x16x32_bf16(af, bf_, acc[nn], 0, 0, 0);
      }
    }
  }

  const int d = wid * 16 + (lane >> 4) * 4;
  const int e = lane & 15;
  float* up = Upart + ((size_t)(chunk * 64 + nh) * 64) * 64;
#pragma unroll
  for (int nn = 0; nn < 4; ++nn)
#pragma unroll
    for (int j = 0; j < 4; ++j)
      up[(size_t)(d + j) * 64 + nn * 16 + e] = acc[nn][j];
  if (e == 0)
#pragma unroll
    for (int j = 0; j < 4; ++j)
      cspart[((size_t)chunk * 64 + nh) * 64 + d + j] = acc[4][j];
}

// ---------------------------------------------------------------- ctx build
__global__ void ctxbuild(const float* __restrict__ Upart,
                         const float* __restrict__ cspart,
                         unsigned short* __restrict__ ctxT) {  // [64 nh][64 e][64 d]
  const int nh = blockIdx.x, tid = threadIdx.x;
  __shared__ float cs[64];
  if (tid < 64) {
    float s = 0;
    for (int c = 0; c < 8; ++c) s += cspart[((size_t)c * 64 + nh) * 64 + tid];
    cs[tid] = s;
  }
  __syncthreads();
  const int d0 = (tid >> 4) * 4, e0 = (tid & 15) * 4;
#pragma unroll
  for (int i = 0; i < 4; ++i) {
    const float inv = 0.125f / cs[d0 + i];   // 1/(sqrt(64)*colsum)
#pragma unroll
    for (int j = 0; j < 4; ++j) {
      float s = 0;
      for (int c = 0; c < 8; ++c)
        s += Upart[((size_t)(c * 64 + nh) * 64 + d0 + i) * 64 + e0 + j];
      ctxT[((size_t)nh * 64 + (e0 + j)) * 64 + (d0 + i)] = f2bf(s * inv);
    }
  }
}

// ---------------------------------------------------------------- out: softmax_feat(qp) @ ctx
__global__ __launch_bounds__(256) void outk(
    const unsigned short* __restrict__ Pq,
    const unsigned short* __restrict__ ctxT,
    float* __restrict__ Out) {
  const int tb = blockIdx.x;
  const int nh = blockIdx.y;
  const int n = nh >> 4, h = nh & 15;
  const int tid = threadIdx.x, lane = tid & 63, wid = tid >> 6;
  __shared__ unsigned short sp[128][72];

  bf16x8 breg[2][4];
#pragma unroll
  for (int ks = 0; ks < 2; ++ks)
#pragma unroll
    for (int nn = 0; nn < 4; ++nn)
      breg[ks][nn] = *(const bf16x8*)(ctxT + ((size_t)nh * 64 + nn * 16 + (lane & 15)) * 64
                                      + ks * 32 + (lane >> 4) * 8);

  const int r = tid >> 1, half = tid & 1;
  const int t0 = tb * 128;
  const size_t qoff = (size_t)(n * T_ + t0 + r) * H_ + h * DH + half * 32;
  u16x8 qv[4];
#pragma unroll
  for (int s = 0; s < 4; ++s) qv[s] = *(const u16x8*)(Pq + qoff + s * 8);
  float e[32]; float sum = 0.f;
#pragma unroll
  for (int s = 0; s < 4; ++s)
#pragma unroll
    for (int j = 0; j < 8; ++j) { float x = __expf(bf2f(qv[s][j])); e[s * 8 + j] = x; sum += x; }
  sum += __shfl_xor(sum, 1);
  const float inv = 1.f / sum;
#pragma unroll
  for (int s = 0; s < 4; ++s) {
    u16x8 pb;
#pragma unroll
    for (int j = 0; j < 8; ++j) pb[j] = f2bf(e[s * 8 + j] * inv);
    *(u16x8*)&sp[r][half * 32 + s * 8] = pb;
  }
  __syncthreads();

  f32x4 acc[2][4];
  f32x4 z = {0.f, 0.f, 0.f, 0.f};
#pragma unroll
  for (int mm = 0; mm < 2; ++mm)
#pragma unroll
    for (int nn = 0; nn < 4; ++nn) acc[mm][nn] = z;
  const int wm = wid * 32;
#pragma unroll
  for (int ks = 0; ks < 2; ++ks) {
    bf16x8 av[2];
#pragma unroll
    for (int mm = 0; mm < 2; ++mm)
      av[mm] = *(const bf16x8*)((const char*)&sp[0][0]
               + (wm + mm * 16 + (lane & 15)) * 144 + ks * 64 + (lane >> 4) * 16);
#pragma unroll
    for (int mm = 0; mm < 2; ++mm)
#pragma unroll
      for (int nn = 0; nn < 4; ++nn)
        acc[mm][nn] = __builtin_amdgcn_mfma_f32_16x16x32_bf16(av[mm], breg[ks][nn], acc[mm][nn], 0, 0, 0);
  }

#pragma unroll
  for (int mm = 0; mm < 2; ++mm)
#pragma unroll
    for (int j = 0; j < 4; ++j) {
      const int row = t0 + wm + mm * 16 + (lane >> 4) * 4 + j;
      float* op = Out + ((size_t)n * T_ + row) * H_ + h * DH + (lane & 15);
#pragma unroll
      for (int nn = 0; nn < 4; ++nn) op[nn * 16] = acc[mm][nn][j];
    }
}

// ---------------------------------------------------------------- launch
extern "C" void kernel_launch(void* const* d_in, const int* in_sizes, int n_in,
                              void* d_out, int out_size, void* d_ws, size_t ws_size,
                              hipStream_t stream) {
  const float* q  = (const float*)d_in[0];
  const float* k  = (const float*)d_in[1];
  const float* v  = (const float*)d_in[2];
  // d_in[3] = mask_q: per-row constant before feature-dim softmax -> provably a no-op
  const float* mask_attn = (const float*)d_in[4];
  const float* Wq = (const float*)d_in[5];
  const float* bq = (const float*)d_in[6];
  const float* Wk = (const float*)d_in[7];
  const float* bk = (const float*)d_in[8];
  const float* Wv = (const float*)d_in[9];
  const float* bv = (const float*)d_in[10];
  float* out = (float*)d_out;

  char* ws = (char*)d_ws;
  size_t off = 0;
  unsigned short* Xb = (unsigned short*)(ws + off); off += (size_t)BT * H_ * 2;       // 64 MB
  unsigned short* Wb = (unsigned short*)(ws + off); off += (size_t)3 * H_ * H_ * 2;   // 6 MB
  unsigned short* Pq = (unsigned short*)(ws + off); off += (size_t)BT * H_ * 2;
  unsigned short* Pk = (unsigned short*)(ws + off); off += (size_t)BT * H_ * 2;
  unsigned short* Pv = (unsigned short*)(ws + off); off += (size_t)BT * H_ * 2;
  float* Upart  = (float*)(ws + off); off += (size_t)8 * 64 * 64 * 64 * 4;            // 8 MB
  float* cspart = (float*)(ws + off); off += (size_t)8 * 64 * 64 * 4;
  unsigned short* ctxT = (unsigned short*)(ws + off); off += (size_t)64 * 64 * 64 * 2;

  dim3 blk(256);
  const int nW4 = H_ * H_ / 4;
  cvt_kernel<<<dim3(512), blk, 0, stream>>>(Wq, Wb + 0 * H_ * H_, nW4);
  cvt_kernel<<<dim3(512), blk, 0, stream>>>(Wk, Wb + 1 * H_ * H_, nW4);
  cvt_kernel<<<dim3(512), blk, 0, stream>>>(Wv, Wb + 2 * H_ * H_, nW4);

  const int nX4 = BT * H_ / 4;
  dim3 ggrid(8, 256);   // N/128, M/128 (gemm128 swizzle assumes this shape)
  cvt_kernel<<<dim3(2048), blk, 0, stream>>>(k, Xb, nX4);
  gemm128<<<ggrid, blk, 0, stream>>>(Xb, Wb + 1 * H_ * H_, bk, Pk);
  cvt_kernel<<<dim3(2048), blk, 0, stream>>>(v, Xb, nX4);
  gemm128<<<ggrid, blk, 0, stream>>>(Xb, Wb + 2 * H_ * H_, bv, Pv);
  cvt_kernel<<<dim3(2048), blk, 0, stream>>>(q, Xb, nX4);
  gemm128<<<ggrid, blk, 0, stream>>>(Xb, Wb + 0 * H_ * H_, bq, Pq);

  phase1<<<dim3(8, 64), blk, 0, stream>>>(Pk, Pv, mask_attn, Upart, cspart);
  ctxbuild<<<dim3(64), blk, 0, stream>>>(Upart, cspart, ctxT);
  outk<<<dim3(64, 64), blk, 0, stream>>>(Pq, ctxT, out);
}